// Round 1
// baseline (1413.061 us; speedup 1.0000x reference)
//
#include <hip/hip_runtime.h>
#include <hip/hip_bf16.h>
#include <math.h>

#define T_TOKENS 8192
#define DDIM 1024
#define HDIM 4096
#define NEXP 8
#define CAP 8192   // max tokens per expert (each token contributes to an expert at most once)

typedef __bf16 bf16;
typedef __bf16 bf16x4 __attribute__((ext_vector_type(4)));
typedef __bf16 bf16x8 __attribute__((ext_vector_type(8)));
typedef float  floatx4 __attribute__((ext_vector_type(4)));

// ---------------------------------------------------------------------------
// Kernel 1: router. One 64-lane wave per token.
// Computes fp32 logits (written to output), top-2 selection (tie-break =
// lowest index, matching jax.lax.top_k), renormalized weights, and per-expert
// slot assignment via atomic counters.
// ---------------------------------------------------------------------------
__global__ void router_kernel(const float* __restrict__ x,
                              const float* __restrict__ gw,
                              const float* __restrict__ gbias,
                              float* __restrict__ logits_out,
                              int* counts, int* token_of,
                              int* selpack, int* slots, float* wts)
{
    int t = blockIdx.x;
    int l = threadIdx.x;  // 0..63
    const float4* xr = (const float4*)(x + (size_t)t * DDIM);

    float p[NEXP];
#pragma unroll
    for (int e = 0; e < NEXP; ++e) p[e] = 0.f;

#pragma unroll
    for (int it = 0; it < 4; ++it) {
        int d4 = it * 64 + l;          // float4 index into row
        float4 v = xr[d4];
        float vv[4] = {v.x, v.y, v.z, v.w};
#pragma unroll
        for (int j = 0; j < 4; ++j) {
            const float4* g4 = (const float4*)(gw + (size_t)(d4 * 4 + j) * NEXP);
            float4 ga = g4[0], gb4 = g4[1];
            p[0] += vv[j] * ga.x;  p[1] += vv[j] * ga.y;
            p[2] += vv[j] * ga.z;  p[3] += vv[j] * ga.w;
            p[4] += vv[j] * gb4.x; p[5] += vv[j] * gb4.y;
            p[6] += vv[j] * gb4.z; p[7] += vv[j] * gb4.w;
        }
    }
#pragma unroll
    for (int e = 0; e < NEXP; ++e) {
#pragma unroll
        for (int off = 32; off; off >>= 1) p[e] += __shfl_xor(p[e], off);
        p[e] += gbias[e];
    }
    if (l < NEXP) logits_out[(size_t)t * NEXP + l] = p[l];

    if (l == 0) {
        int e0 = 0;
#pragma unroll
        for (int e = 1; e < NEXP; ++e) if (p[e] > p[e0]) e0 = e;
        int e1 = -1;
#pragma unroll
        for (int e = 0; e < NEXP; ++e) {
            if (e == e0) continue;
            if (e1 < 0 || p[e] > p[e1]) e1 = e;
        }
        // renormalized top-2 softmax weights: w0 = e^l0/(e^l0+e^l1)
        float w0 = 1.f / (1.f + expf(p[e1] - p[e0]));
        float w1 = 1.f / (1.f + expf(p[e0] - p[e1]));
        int s0 = atomicAdd(&counts[e0], 1);
        int s1 = atomicAdd(&counts[e1], 1);
        token_of[e0 * CAP + s0] = t;
        token_of[e1 * CAP + s1] = t;
        selpack[t] = e0 | (e1 << 8);
        slots[2 * t]     = s0;
        slots[2 * t + 1] = s1;
        wts[2 * t]     = w0;
        wts[2 * t + 1] = w1;
    }
}

// ---------------------------------------------------------------------------
// Kernel 2: exclusive prefix sum of the 8 counts.
// ---------------------------------------------------------------------------
__global__ void offsets_kernel(const int* __restrict__ counts, int* __restrict__ offsets)
{
    if (threadIdx.x == 0) {
        int a = 0;
#pragma unroll
        for (int e = 0; e < NEXP; ++e) { offsets[e] = a; a += counts[e]; }
        offsets[NEXP] = a;
    }
}

// ---------------------------------------------------------------------------
// Kernel 3: gather token rows -> compact bf16 A matrix, grouped by expert.
// One wave per (expert, slot); blocks past count[e] exit.
// ---------------------------------------------------------------------------
__global__ void gather_kernel(const float* __restrict__ x,
                              const int* __restrict__ counts,
                              const int* __restrict__ offsets,
                              const int* __restrict__ token_of,
                              bf16* __restrict__ xg)
{
    int e = blockIdx.y, s = blockIdx.x;
    if (s >= counts[e]) return;
    int t   = token_of[e * CAP + s];
    int row = offsets[e] + s;
    const float4* src = (const float4*)(x + (size_t)t * DDIM);
    bf16x4* dst = (bf16x4*)(xg + (size_t)row * DDIM);
    int l = threadIdx.x;
#pragma unroll
    for (int it = 0; it < 4; ++it) {
        float4 v = src[it * 64 + l];
        bf16x4 b;
        b[0] = (bf16)v.x; b[1] = (bf16)v.y; b[2] = (bf16)v.z; b[3] = (bf16)v.w;
        dst[it * 64 + l] = b;
    }
}

// ---------------------------------------------------------------------------
// Kernel 4: per-expert transpose + fp32->bf16 convert.
// in: [E][R][C] fp32 row-major  ->  out: [E][C][R] bf16 row-major.
// Makes the GEMM B-operand k-contiguous (MFMA B fragment = 8 contiguous k).
// ---------------------------------------------------------------------------
__global__ void transpose_cvt_kernel(const float* __restrict__ in,
                                     bf16* __restrict__ out, int R, int C)
{
    __shared__ float tile[32][33];
    int e = blockIdx.z;
    const float* src = in + (size_t)e * R * C;
    bf16* dst = out + (size_t)e * R * C;
    int c0 = blockIdx.x * 32, r0 = blockIdx.y * 32;
    int tx = threadIdx.x, ty = threadIdx.y;   // 32 x 8
#pragma unroll
    for (int j = 0; j < 4; ++j) {
        int r = r0 + ty + j * 8;
        tile[ty + j * 8][tx] = src[(size_t)r * C + c0 + tx];
    }
    __syncthreads();
#pragma unroll
    for (int j = 0; j < 4; ++j) {
        int c = c0 + ty + j * 8;
        dst[(size_t)c * R + r0 + tx] = (bf16)tile[tx][ty + j * 8];
    }
}

// ---------------------------------------------------------------------------
// MFMA GEMM over compact per-expert rows.
// A: [rows, KTOT] bf16 (k contiguous).  B: [E][NTOT][KTOT] bf16 (k contiguous,
// i.e. pre-transposed weights).  Out[row, NTOT] (+bias, optional exact GELU).
// 128x128 tile, BK=64, 4 waves, each wave 64x64 via 4x4 mfma_16x16x32 tiles.
// Grid: (64 max row tiles, NTOT/128, E); blocks past count[e] exit early.
// LDS stride 72 (+8 bf16 pad): keeps ds_read_b128 16B-aligned, <=2-way banks.
// ---------------------------------------------------------------------------
template<int KTOT, int NTOT, bool DOGELU, typename OutT>
__global__ __launch_bounds__(256, 2)
void moe_gemm(const bf16* __restrict__ Abase, const bf16* __restrict__ Bbase,
              const float* __restrict__ bias, OutT* __restrict__ Out,
              const int* __restrict__ counts, const int* __restrict__ offsets)
{
    int e = blockIdx.z;
    int cnt = counts[e];
    int rows_done = blockIdx.x * 128;
    if (rows_done >= cnt) return;
    int valid = cnt - rows_done; if (valid > 128) valid = 128;
    int row0 = offsets[e] + rows_done;
    int n0 = blockIdx.y * 128;

    const bf16* A = Abase + (size_t)row0 * KTOT;
    const bf16* B = Bbase + (size_t)e * NTOT * KTOT + (size_t)n0 * KTOT;
    const float* bvec = bias + (size_t)e * NTOT + n0;

    __shared__ __align__(16) bf16 As[128][72];
    __shared__ __align__(16) bf16 Bs[128][72];

    int tid = threadIdx.x;
    int lane = tid & 63, wave = tid >> 6;
    int wr = wave >> 1, wc = wave & 1;
    int m16 = lane & 15, quad = lane >> 4;

    floatx4 acc[4][4];
#pragma unroll
    for (int i = 0; i < 4; ++i)
#pragma unroll
        for (int j = 0; j < 4; ++j)
#pragma unroll
            for (int r = 0; r < 4; ++r) acc[i][j][r] = 0.f;

    bf16x8 zero8;
#pragma unroll
    for (int q = 0; q < 8; ++q) zero8[q] = (bf16)0.f;

    for (int k0 = 0; k0 < KTOT; k0 += 64) {
        // stage A tile (128 rows x 64 k), zero rows past 'valid'
#pragma unroll
        for (int it = 0; it < 4; ++it) {
            int c = tid + it * 256;
            int r = c >> 3, kk = (c & 7) * 8;
            bf16x8 v = zero8;
            if (r < valid) v = *(const bf16x8*)(A + (size_t)r * KTOT + k0 + kk);
            *(bf16x8*)(&As[r][kk]) = v;
        }
        // stage B tile (128 n-rows x 64 k)
#pragma unroll
        for (int it = 0; it < 4; ++it) {
            int c = tid + it * 256;
            int r = c >> 3, kk = (c & 7) * 8;
            *(bf16x8*)(&Bs[r][kk]) = *(const bf16x8*)(B + (size_t)r * KTOT + k0 + kk);
        }
        __syncthreads();
#pragma unroll
        for (int ks = 0; ks < 64; ks += 32) {
            bf16x8 af[4], bfr[4];
#pragma unroll
            for (int i = 0; i < 4; ++i)
                af[i] = *(const bf16x8*)(&As[wr * 64 + i * 16 + m16][ks + quad * 8]);
#pragma unroll
            for (int j = 0; j < 4; ++j)
                bfr[j] = *(const bf16x8*)(&Bs[wc * 64 + j * 16 + m16][ks + quad * 8]);
#pragma unroll
            for (int i = 0; i < 4; ++i)
#pragma unroll
                for (int j = 0; j < 4; ++j)
                    acc[i][j] = __builtin_amdgcn_mfma_f32_16x16x32_bf16(
                        af[i], bfr[j], acc[i][j], 0, 0, 0);
        }
        __syncthreads();
    }

    // epilogue: C/D layout col = lane&15, row = quad*4 + reg  [m89-verified]
#pragma unroll
    for (int i = 0; i < 4; ++i) {
#pragma unroll
        for (int r = 0; r < 4; ++r) {
            int lrow = wr * 64 + i * 16 + quad * 4 + r;
            if (lrow >= valid) continue;
            size_t orow = (size_t)(row0 + lrow) * NTOT + n0;
#pragma unroll
            for (int j = 0; j < 4; ++j) {
                int lcol = wc * 64 + j * 16 + m16;
                float v = acc[i][j][r] + bvec[lcol];
                if (DOGELU)
                    v = 0.5f * v * (1.f + erff(v * 0.70710678118654752f));
                Out[orow + lcol] = (OutT)v;
            }
        }
    }
}

// ---------------------------------------------------------------------------
// Kernel 7: combine. out[t] = w0*y[pos0] + w1*y[pos1]  (bias already applied).
// ---------------------------------------------------------------------------
__global__ void combine_kernel(const float* __restrict__ y,
                               const int* __restrict__ offsets,
                               const int* __restrict__ selpack,
                               const int* __restrict__ slots,
                               const float* __restrict__ wts,
                               float* __restrict__ out)
{
    int t = blockIdx.x;
    int sp = selpack[t];
    int e0 = sp & 0xff, e1 = (sp >> 8) & 0xff;
    int p0 = offsets[e0] + slots[2 * t];
    int p1 = offsets[e1] + slots[2 * t + 1];
    float w0 = wts[2 * t], w1 = wts[2 * t + 1];
    const float4* y0 = (const float4*)(y + (size_t)p0 * DDIM);
    const float4* y1 = (const float4*)(y + (size_t)p1 * DDIM);
    float4* o = (float4*)(out + (size_t)t * DDIM);
    int tid = threadIdx.x;  // 256 threads x float4 = 1024
    float4 a = y0[tid], b = y1[tid];
    float4 rr;
    rr.x = w0 * a.x + w1 * b.x;
    rr.y = w0 * a.y + w1 * b.y;
    rr.z = w0 * a.z + w1 * b.z;
    rr.w = w0 * a.w + w1 * b.w;
    o[tid] = rr;
}

// ---------------------------------------------------------------------------
extern "C" void kernel_launch(void* const* d_in, const int* in_sizes, int n_in,
                              void* d_out, int out_size, void* d_ws, size_t ws_size,
                              hipStream_t stream)
{
    (void)in_sizes; (void)n_in; (void)out_size; (void)ws_size;
    const float* x  = (const float*)d_in[0];
    const float* gw = (const float*)d_in[1];
    const float* gb = (const float*)d_in[2];
    const float* w1 = (const float*)d_in[3];
    const float* b1 = (const float*)d_in[4];
    const float* w2 = (const float*)d_in[5];
    const float* b2 = (const float*)d_in[6];
    float* out    = (float*)d_out;
    float* logits = out + (size_t)T_TOKENS * DDIM;

    char* ws = (char*)d_ws;
    const size_t MB = 1024 * 1024;
    int*   counts   = (int*)(ws + 0);                 // 32 B
    int*   offsets  = (int*)(ws + 256);               // 36 B
    int*   selpack  = (int*)(ws + 512);               // 32 KB
    int*   slots    = (int*)(ws + 512 + 32 * 1024);   // 64 KB
    float* wts      = (float*)(ws + 512 + 96 * 1024); // 64 KB
    int*   token_of = (int*)(ws + 512 + 160 * 1024);  // 256 KB
    bf16*  xg  = (bf16*)(ws + 1 * MB);    // 16384 x 1024 bf16 = 32 MB
    bf16*  w1b = (bf16*)(ws + 33 * MB);   // [E][H][D] bf16    = 64 MB
    bf16*  w2b = (bf16*)(ws + 97 * MB);   // [E][D][H] bf16    = 64 MB
    bf16*  mid = (bf16*)(ws + 161 * MB);  // 16384 x 4096 bf16 = 128 MB
    float* y   = (float*)(ws + 289 * MB); // 16384 x 1024 f32  = 64 MB
    // total ws use: 353 MB

    hipMemsetAsync(counts, 0, 32, stream);

    router_kernel<<<T_TOKENS, 64, 0, stream>>>(x, gw, gb, logits, counts,
                                               token_of, selpack, slots, wts);
    offsets_kernel<<<1, 64, 0, stream>>>(counts, offsets);
    gather_kernel<<<dim3(CAP, NEXP), 64, 0, stream>>>(x, counts, offsets, token_of, xg);
    // w1: [E][1024][4096] -> w1b [E][4096][1024]
    transpose_cvt_kernel<<<dim3(HDIM / 32, DDIM / 32, NEXP), dim3(32, 8), 0, stream>>>(
        w1, w1b, DDIM, HDIM);
    // w2: [E][4096][1024] -> w2b [E][1024][4096]
    transpose_cvt_kernel<<<dim3(DDIM / 32, HDIM / 32, NEXP), dim3(32, 8), 0, stream>>>(
        w2, w2b, HDIM, DDIM);
    // GEMM1: mid = gelu(xg @ w1[e] + b1[e])   [rows x 4096] bf16
    moe_gemm<DDIM, HDIM, true, bf16><<<dim3(64, HDIM / 128, NEXP), 256, 0, stream>>>(
        xg, w1b, b1, mid, counts, offsets);
    // GEMM2: y = mid @ w2[e] + b2[e]          [rows x 1024] fp32
    moe_gemm<HDIM, DDIM, false, float><<<dim3(64, DDIM / 128, NEXP), 256, 0, stream>>>(
        mid, w2b, b2, y, counts, offsets);
    combine_kernel<<<T_TOKENS, 256, 0, stream>>>(y, offsets, selpack, slots, wts, out);
}

// Round 2
// 1175.561 us; speedup vs baseline: 1.2020x; 1.2020x over previous
//
#include <hip/hip_runtime.h>
#include <hip/hip_bf16.h>
#include <math.h>

#define T_TOKENS 8192
#define DDIM 1024
#define HDIM 4096
#define NEXP 8
#define CAP 8192   // max tokens per expert

typedef __bf16 bf16;
typedef __bf16 bf16x2 __attribute__((ext_vector_type(2)));
typedef __bf16 bf16x4 __attribute__((ext_vector_type(4)));
typedef __bf16 bf16x8 __attribute__((ext_vector_type(8)));
typedef float  floatx4 __attribute__((ext_vector_type(4)));

// async global->LDS, 16 bytes per lane. LDS dest is wave-uniform base +
// lane*16 (m104/m108) — pass the wave-uniform base, per-lane global addr.
__device__ static inline void async_load16(const void* g, void* l)
{
    __builtin_amdgcn_global_load_lds(
        (const __attribute__((address_space(1))) void*)g,
        (__attribute__((address_space(3))) void*)l, 16, 0, 0);
}

// ---------------------------------------------------------------------------
// Kernel 1: router. One 64-lane wave per token. fp32 logits (exact), top-2
// (tie-break lowest index = jax.lax.top_k), renormalized weights, slot assign.
// ---------------------------------------------------------------------------
__global__ void router_kernel(const float* __restrict__ x,
                              const float* __restrict__ gw,
                              const float* __restrict__ gbias,
                              float* __restrict__ logits_out,
                              int* counts, int* token_of,
                              int* selpack, int* slots, float* wts)
{
    int t = blockIdx.x;
    int l = threadIdx.x;  // 0..63
    const float4* xr = (const float4*)(x + (size_t)t * DDIM);

    float p[NEXP];
#pragma unroll
    for (int e = 0; e < NEXP; ++e) p[e] = 0.f;

#pragma unroll
    for (int it = 0; it < 4; ++it) {
        int d4 = it * 64 + l;
        float4 v = xr[d4];
        float vv[4] = {v.x, v.y, v.z, v.w};
#pragma unroll
        for (int j = 0; j < 4; ++j) {
            const float4* g4 = (const float4*)(gw + (size_t)(d4 * 4 + j) * NEXP);
            float4 ga = g4[0], gb4 = g4[1];
            p[0] += vv[j] * ga.x;  p[1] += vv[j] * ga.y;
            p[2] += vv[j] * ga.z;  p[3] += vv[j] * ga.w;
            p[4] += vv[j] * gb4.x; p[5] += vv[j] * gb4.y;
            p[6] += vv[j] * gb4.z; p[7] += vv[j] * gb4.w;
        }
    }
#pragma unroll
    for (int e = 0; e < NEXP; ++e) {
#pragma unroll
        for (int off = 32; off; off >>= 1) p[e] += __shfl_xor(p[e], off);
        p[e] += gbias[e];
    }
    if (l < NEXP) logits_out[(size_t)t * NEXP + l] = p[l];

    if (l == 0) {
        int e0 = 0;
#pragma unroll
        for (int e = 1; e < NEXP; ++e) if (p[e] > p[e0]) e0 = e;
        int e1 = -1;
#pragma unroll
        for (int e = 0; e < NEXP; ++e) {
            if (e == e0) continue;
            if (e1 < 0 || p[e] > p[e1]) e1 = e;
        }
        float w0 = 1.f / (1.f + expf(p[e1] - p[e0]));
        float w1 = 1.f / (1.f + expf(p[e0] - p[e1]));
        int s0 = atomicAdd(&counts[e0], 1);
        int s1 = atomicAdd(&counts[e1], 1);
        token_of[e0 * CAP + s0] = t;
        token_of[e1 * CAP + s1] = t;
        selpack[t] = e0 | (e1 << 8);
        slots[2 * t]     = s0;
        slots[2 * t + 1] = s1;
        wts[2 * t]     = w0;
        wts[2 * t + 1] = w1;
    }
}

// ---------------------------------------------------------------------------
// Kernel 2: exclusive prefix sum of the 8 counts.
// ---------------------------------------------------------------------------
__global__ void offsets_kernel(const int* __restrict__ counts, int* __restrict__ offsets)
{
    if (threadIdx.x == 0) {
        int a = 0;
#pragma unroll
        for (int e = 0; e < NEXP; ++e) { offsets[e] = a; a += counts[e]; }
        offsets[NEXP] = a;
    }
}

// ---------------------------------------------------------------------------
// Kernel 3: gather token rows -> compact bf16 A matrix, grouped by expert.
// ---------------------------------------------------------------------------
__global__ void gather_kernel(const float* __restrict__ x,
                              const int* __restrict__ counts,
                              const int* __restrict__ offsets,
                              const int* __restrict__ token_of,
                              bf16* __restrict__ xg)
{
    int e = blockIdx.y, s = blockIdx.x;
    if (s >= counts[e]) return;
    int t   = token_of[e * CAP + s];
    int row = offsets[e] + s;
    const float4* src = (const float4*)(x + (size_t)t * DDIM);
    bf16x4* dst = (bf16x4*)(xg + (size_t)row * DDIM);
    int l = threadIdx.x;
#pragma unroll
    for (int it = 0; it < 4; ++it) {
        float4 v = src[it * 64 + l];
        bf16x4 b;
        b[0] = (bf16)v.x; b[1] = (bf16)v.y; b[2] = (bf16)v.z; b[3] = (bf16)v.w;
        dst[it * 64 + l] = b;
    }
}

// ---------------------------------------------------------------------------
// Kernel 4: per-expert transpose + fp32->bf16.
// in: [E][R][C] fp32 -> out: [E][C][R] bf16 (k-contiguous B operand).
// 64(r) x 32(c) tile; bf16x2 stores for full write coalescing.
// ---------------------------------------------------------------------------
__global__ void transpose_cvt_kernel(const float* __restrict__ in,
                                     bf16* __restrict__ out, int R, int C)
{
    __shared__ bf16 tile[32][66];   // [c][r], stride 66 bf16 = 33 dwords
    int e = blockIdx.z;
    const float* src = in + (size_t)e * R * C;
    bf16* dst = out + (size_t)e * R * C;
    int c0 = blockIdx.x * 32, r0 = blockIdx.y * 64;
    int tx = threadIdx.x, ty = threadIdx.y;   // 32 x 8
#pragma unroll
    for (int j = 0; j < 8; ++j) {
        int rr = ty + j * 8;
        tile[tx][rr] = (bf16)src[(size_t)(r0 + rr) * C + c0 + tx];
    }
    __syncthreads();
#pragma unroll
    for (int j = 0; j < 4; ++j) {
        int cc = ty + j * 8;
        int rr = tx * 2;
        bf16x2 v;
        v[0] = tile[cc][rr];
        v[1] = tile[cc][rr + 1];
        *(bf16x2*)(dst + (size_t)(c0 + cc) * R + r0 + rr) = v;
    }
}

// ---------------------------------------------------------------------------
// Stage one 128x64 bf16 tile into unpadded LDS via global_load_lds, with
// XOR chunk swizzle on the GLOBAL side: phys chunk p holds logical chunk
// p ^ (row&7). Later b128 fragment reads then touch 8 distinct bank-quads
// (<=2-way, free). Rows >= valid are clamped (outputs there never written).
// ---------------------------------------------------------------------------
template<int KTOT>
__device__ static inline void stage_tile(const bf16* __restrict__ gbase,
                                         bf16* lds, int wave, int lane, int valid)
{
#pragma unroll
    for (int it = 0; it < 4; ++it) {
        int rbase = wave * 32 + it * 8;          // wave-uniform
        int rloc  = rbase + (lane >> 3);
        int grow  = rloc < valid ? rloc : (valid - 1);
        int chunk = (lane & 7) ^ (rloc & 7);
        const bf16* g = gbase + (size_t)grow * KTOT + chunk * 8;
        async_load16(g, lds + rbase * 64);       // lane i -> base + i*16B
    }
}

// ---------------------------------------------------------------------------
// MFMA GEMM over compact per-expert rows (m97-style staging).
// A: [rows, KTOT] bf16.  B: [E][NTOT][KTOT] bf16 (pre-transposed weights).
// 128x128 tile, BK=64, 4 waves x (64x64 via 4x4 mfma_16x16x32).
// LDS: unpadded 128x64 per operand (16 KB each), XOR-swizzled chunks.
// ---------------------------------------------------------------------------
template<int KTOT, int NTOT, bool DOGELU, typename OutT>
__global__ __launch_bounds__(256, 4)
void moe_gemm(const bf16* __restrict__ Abase, const bf16* __restrict__ Bbase,
              const float* __restrict__ bias, OutT* __restrict__ Out,
              const int* __restrict__ counts, const int* __restrict__ offsets)
{
    int e = blockIdx.z;
    int cnt = counts[e];
    int rows_done = blockIdx.x * 128;
    if (rows_done >= cnt) return;
    int valid = cnt - rows_done; if (valid > 128) valid = 128;
    int row0 = offsets[e] + rows_done;
    int n0 = blockIdx.y * 128;

    const bf16* A = Abase + (size_t)row0 * KTOT;
    const bf16* B = Bbase + (size_t)e * NTOT * KTOT + (size_t)n0 * KTOT;
    const float* bvec = bias + (size_t)e * NTOT + n0;

    __shared__ __align__(16) bf16 As[128 * 64];
    __shared__ __align__(16) bf16 Bs[128 * 64];

    int tid = threadIdx.x;
    int lane = tid & 63, wave = tid >> 6;
    int wr = wave >> 1, wc = wave & 1;
    int m16 = lane & 15, quad = lane >> 4;
    int swz = m16 & 7;   // row&7 for all fragment rows this lane touches

    floatx4 acc[4][4];
#pragma unroll
    for (int i = 0; i < 4; ++i)
#pragma unroll
        for (int j = 0; j < 4; ++j)
#pragma unroll
            for (int r = 0; r < 4; ++r) acc[i][j][r] = 0.f;

    for (int k0 = 0; k0 < KTOT; k0 += 64) {
        stage_tile<KTOT>(A + k0, As, wave, lane, valid);
        stage_tile<KTOT>(B + k0, Bs, wave, lane, 128);
        __syncthreads();   // emits s_waitcnt vmcnt(0) before s_barrier
#pragma unroll
        for (int ks = 0; ks < 64; ks += 32) {
            int cbase = (ks >> 3) + quad;        // logical chunk 0..7
            int pchunk = (cbase ^ swz) * 8;      // phys bf16 offset in row
            bf16x8 af[4], bfr[4];
#pragma unroll
            for (int i = 0; i < 4; ++i)
                af[i] = *(const bf16x8*)(&As[(wr * 64 + i * 16 + m16) * 64 + pchunk]);
#pragma unroll
            for (int j = 0; j < 4; ++j)
                bfr[j] = *(const bf16x8*)(&Bs[(wc * 64 + j * 16 + m16) * 64 + pchunk]);
#pragma unroll
            for (int i = 0; i < 4; ++i)
#pragma unroll
                for (int j = 0; j < 4; ++j)
                    acc[i][j] = __builtin_amdgcn_mfma_f32_16x16x32_bf16(
                        af[i], bfr[j], acc[i][j], 0, 0, 0);
        }
        __syncthreads();
    }

    // epilogue: C/D layout col = lane&15, row = quad*4 + reg  [m89-verified]
#pragma unroll
    for (int i = 0; i < 4; ++i) {
#pragma unroll
        for (int r = 0; r < 4; ++r) {
            int lrow = wr * 64 + i * 16 + quad * 4 + r;
            if (lrow >= valid) continue;
            size_t orow = (size_t)(row0 + lrow) * NTOT + n0;
#pragma unroll
            for (int j = 0; j < 4; ++j) {
                int lcol = wc * 64 + j * 16 + m16;
                float v = acc[i][j][r] + bvec[lcol];
                if (DOGELU)
                    v = 0.5f * v * (1.f + erff(v * 0.70710678118654752f));
                Out[orow + lcol] = (OutT)v;
            }
        }
    }
}

// ---------------------------------------------------------------------------
// Kernel 7: combine. out[t] = w0*y[pos0] + w1*y[pos1].
// ---------------------------------------------------------------------------
__global__ void combine_kernel(const float* __restrict__ y,
                               const int* __restrict__ offsets,
                               const int* __restrict__ selpack,
                               const int* __restrict__ slots,
                               const float* __restrict__ wts,
                               float* __restrict__ out)
{
    int t = blockIdx.x;
    int sp = selpack[t];
    int e0 = sp & 0xff, e1 = (sp >> 8) & 0xff;
    int p0 = offsets[e0] + slots[2 * t];
    int p1 = offsets[e1] + slots[2 * t + 1];
    float w0 = wts[2 * t], w1 = wts[2 * t + 1];
    const float4* y0 = (const float4*)(y + (size_t)p0 * DDIM);
    const float4* y1 = (const float4*)(y + (size_t)p1 * DDIM);
    float4* o = (float4*)(out + (size_t)t * DDIM);
    int tid = threadIdx.x;
    float4 a = y0[tid], b = y1[tid];
    float4 rr;
    rr.x = w0 * a.x + w1 * b.x;
    rr.y = w0 * a.y + w1 * b.y;
    rr.z = w0 * a.z + w1 * b.z;
    rr.w = w0 * a.w + w1 * b.w;
    o[tid] = rr;
}

// ---------------------------------------------------------------------------
extern "C" void kernel_launch(void* const* d_in, const int* in_sizes, int n_in,
                              void* d_out, int out_size, void* d_ws, size_t ws_size,
                              hipStream_t stream)
{
    (void)in_sizes; (void)n_in; (void)out_size; (void)ws_size;
    const float* x  = (const float*)d_in[0];
    const float* gw = (const float*)d_in[1];
    const float* gb = (const float*)d_in[2];
    const float* w1 = (const float*)d_in[3];
    const float* b1 = (const float*)d_in[4];
    const float* w2 = (const float*)d_in[5];
    const float* b2 = (const float*)d_in[6];
    float* out    = (float*)d_out;
    float* logits = out + (size_t)T_TOKENS * DDIM;

    char* ws = (char*)d_ws;
    const size_t MB = 1024 * 1024;
    int*   counts   = (int*)(ws + 0);
    int*   offsets  = (int*)(ws + 256);
    int*   selpack  = (int*)(ws + 512);
    int*   slots    = (int*)(ws + 512 + 32 * 1024);
    float* wts      = (float*)(ws + 512 + 96 * 1024);
    int*   token_of = (int*)(ws + 512 + 160 * 1024);
    bf16*  xg  = (bf16*)(ws + 1 * MB);    // 32 MB
    bf16*  w1b = (bf16*)(ws + 33 * MB);   // [E][H][D] 64 MB
    bf16*  w2b = (bf16*)(ws + 97 * MB);   // [E][D][H] 64 MB
    bf16*  mid = (bf16*)(ws + 161 * MB);  // 128 MB
    float* y   = (float*)(ws + 289 * MB); // 64 MB

    hipMemsetAsync(counts, 0, 32, stream);

    router_kernel<<<T_TOKENS, 64, 0, stream>>>(x, gw, gb, logits, counts,
                                               token_of, selpack, slots, wts);
    offsets_kernel<<<1, 64, 0, stream>>>(counts, offsets);
    gather_kernel<<<dim3(CAP, NEXP), 64, 0, stream>>>(x, counts, offsets, token_of, xg);
    // w1: [E][1024][4096] -> w1b [E][4096][1024]
    transpose_cvt_kernel<<<dim3(HDIM / 32, DDIM / 64, NEXP), dim3(32, 8), 0, stream>>>(
        w1, w1b, DDIM, HDIM);
    // w2: [E][4096][1024] -> w2b [E][1024][4096]
    transpose_cvt_kernel<<<dim3(DDIM / 32, HDIM / 64, NEXP), dim3(32, 8), 0, stream>>>(
        w2, w2b, HDIM, DDIM);
    // GEMM1: mid = gelu(xg @ w1[e] + b1[e])
    moe_gemm<DDIM, HDIM, true, bf16><<<dim3(64, HDIM / 128, NEXP), 256, 0, stream>>>(
        xg, w1b, b1, mid, counts, offsets);
    // GEMM2: y = mid @ w2[e] + b2[e]
    moe_gemm<HDIM, DDIM, false, float><<<dim3(64, DDIM / 128, NEXP), 256, 0, stream>>>(
        mid, w2b, b2, y, counts, offsets);
    combine_kernel<<<T_TOKENS, 256, 0, stream>>>(y, offsets, selpack, slots, wts, out);
}

// Round 3
// 970.486 us; speedup vs baseline: 1.4560x; 1.2113x over previous
//
#include <hip/hip_runtime.h>
#include <hip/hip_bf16.h>
#include <math.h>

#define T_TOKENS 8192
#define DDIM 1024
#define HDIM 4096
#define NEXP 8
#define CAP 8192      // max tokens per expert
#define MAXTILES 136  // sum_e ceil(cnt_e/128) <= 128 + 7

typedef __bf16 bf16;
typedef __bf16 bf16x2 __attribute__((ext_vector_type(2)));
typedef __bf16 bf16x4 __attribute__((ext_vector_type(4)));
typedef __bf16 bf16x8 __attribute__((ext_vector_type(8)));
typedef float  floatx4 __attribute__((ext_vector_type(4)));

// async global->LDS, 16 bytes per lane; LDS dest = wave-uniform base + lane*16.
__device__ static inline void async_load16(const void* g, void* l)
{
    __builtin_amdgcn_global_load_lds(
        (const __attribute__((address_space(1))) void*)g,
        (__attribute__((address_space(3))) void*)l, 16, 0, 0);
}

// ---------------------------------------------------------------------------
// Kernel 1: router. One wave per token. fp32 logits (exact; selection matches
// jax.lax.top_k incl. lowest-index tie-break), renormalized top-2 weights.
// ---------------------------------------------------------------------------
__global__ void router_kernel(const float* __restrict__ x,
                              const float* __restrict__ gw,
                              const float* __restrict__ gbias,
                              float* __restrict__ logits_out,
                              int* counts, int* token_of,
                              int* selpack, int* slots, float* wts)
{
    int t = blockIdx.x;
    int l = threadIdx.x;  // 0..63
    const float4* xr = (const float4*)(x + (size_t)t * DDIM);

    float p[NEXP];
#pragma unroll
    for (int e = 0; e < NEXP; ++e) p[e] = 0.f;

#pragma unroll
    for (int it = 0; it < 4; ++it) {
        int d4 = it * 64 + l;
        float4 v = xr[d4];
        float vv[4] = {v.x, v.y, v.z, v.w};
#pragma unroll
        for (int j = 0; j < 4; ++j) {
            const float4* g4 = (const float4*)(gw + (size_t)(d4 * 4 + j) * NEXP);
            float4 ga = g4[0], gb4 = g4[1];
            p[0] += vv[j] * ga.x;  p[1] += vv[j] * ga.y;
            p[2] += vv[j] * ga.z;  p[3] += vv[j] * ga.w;
            p[4] += vv[j] * gb4.x; p[5] += vv[j] * gb4.y;
            p[6] += vv[j] * gb4.z; p[7] += vv[j] * gb4.w;
        }
    }
#pragma unroll
    for (int e = 0; e < NEXP; ++e) {
#pragma unroll
        for (int off = 32; off; off >>= 1) p[e] += __shfl_xor(p[e], off);
        p[e] += gbias[e];
    }
    if (l < NEXP) logits_out[(size_t)t * NEXP + l] = p[l];

    if (l == 0) {
        int e0 = 0;
#pragma unroll
        for (int e = 1; e < NEXP; ++e) if (p[e] > p[e0]) e0 = e;
        int e1 = -1;
#pragma unroll
        for (int e = 0; e < NEXP; ++e) {
            if (e == e0) continue;
            if (e1 < 0 || p[e] > p[e1]) e1 = e;
        }
        float w0 = 1.f / (1.f + expf(p[e1] - p[e0]));
        float w1 = 1.f / (1.f + expf(p[e0] - p[e1]));
        int s0 = atomicAdd(&counts[e0], 1);
        int s1 = atomicAdd(&counts[e1], 1);
        token_of[e0 * CAP + s0] = t;
        token_of[e1 * CAP + s1] = t;
        selpack[t] = e0 | (e1 << 8);
        slots[2 * t]     = s0;
        slots[2 * t + 1] = s1;
        wts[2 * t]     = w0;
        wts[2 * t + 1] = w1;
    }
}

// ---------------------------------------------------------------------------
// Kernel 2: offsets + exact 128-row tile list (kills no-op GEMM blocks).
// tiles[i] = (expert << 24) | global_row0
// ---------------------------------------------------------------------------
__global__ void offsets_kernel(const int* __restrict__ counts,
                               int* __restrict__ offsets,
                               int* __restrict__ tiles,
                               int* __restrict__ ntiles)
{
    if (threadIdx.x == 0) {
        int a = 0, nt = 0;
        for (int e = 0; e < NEXP; ++e) {
            offsets[e] = a;
            for (int r = 0; r < counts[e]; r += 128)
                tiles[nt++] = (e << 24) | (a + r);
            a += counts[e];
        }
        offsets[NEXP] = a;   // == 2*T_TOKENS
        *ntiles = nt;
    }
}

// ---------------------------------------------------------------------------
// Kernel 3: gather over compact rows (total rows == 2*T_TOKENS always).
// 4 waves/block, one row per wave.
// ---------------------------------------------------------------------------
__global__ void gather_kernel(const float* __restrict__ x,
                              const int* __restrict__ offsets,
                              const int* __restrict__ token_of,
                              bf16* __restrict__ xg)
{
    int row = blockIdx.x * 4 + (threadIdx.x >> 6);
    int l = threadIdx.x & 63;
    int e = 0;
#pragma unroll
    for (int i = 1; i < NEXP; ++i) e += (row >= offsets[i]);
    int t = token_of[e * CAP + (row - offsets[e])];
    const float4* src = (const float4*)(x + (size_t)t * DDIM);
    bf16x4* dst = (bf16x4*)(xg + (size_t)row * DDIM);
#pragma unroll
    for (int it = 0; it < 4; ++it) {
        float4 v = src[it * 64 + l];
        bf16x4 b;
        b[0] = (bf16)v.x; b[1] = (bf16)v.y; b[2] = (bf16)v.z; b[3] = (bf16)v.w;
        dst[it * 64 + l] = b;
    }
}

// ---------------------------------------------------------------------------
// Kernel 4: per-expert transpose + fp32->bf16, 16 B/lane both directions.
// in [E][R][C] fp32 -> out [E][C][R] bf16.  64x64 tile, 256 threads.
// ---------------------------------------------------------------------------
__global__ void transpose_cvt_kernel(const float* __restrict__ in,
                                     bf16* __restrict__ out, int R, int C)
{
    __shared__ bf16 tile[64][68];   // [r][c], stride 68 bf16 = 34 dwords
    int e = blockIdx.z;
    const float* src = in + (size_t)e * R * C;
    bf16* dst = out + (size_t)e * R * C;
    int r0 = blockIdx.y * 64, c0 = blockIdx.x * 64;
    int t = threadIdx.x;
    int lr = t >> 4, c4 = t & 15;
#pragma unroll
    for (int it = 0; it < 4; ++it) {
        int r = lr + it * 16;
        float4 v = *(const float4*)(src + (size_t)(r0 + r) * C + c0 + c4 * 4);
        bf16x4 b;
        b[0] = (bf16)v.x; b[1] = (bf16)v.y; b[2] = (bf16)v.z; b[3] = (bf16)v.w;
        *(bf16x4*)(&tile[r][c4 * 4]) = b;
    }
    __syncthreads();
    int oc = t >> 3, rseg = (t & 7) * 8;
#pragma unroll
    for (int it = 0; it < 2; ++it) {
        int c = oc + it * 32;
        bf16x8 v;
#pragma unroll
        for (int j = 0; j < 8; ++j) v[j] = tile[rseg + j][c];
        *(bf16x8*)(dst + (size_t)(c0 + c) * R + r0 + rseg) = v;
    }
}

// ---------------------------------------------------------------------------
// Stage 128x64 bf16 tile -> unpadded LDS via global_load_lds, XOR chunk
// swizzle on the global side (phys chunk p holds logical p ^ (row&7)).
// Rows >= valid clamped (their outputs never written).
// ---------------------------------------------------------------------------
template<int KTOT>
__device__ static inline void stage_tile(const bf16* __restrict__ gbase,
                                         bf16* lds, int wave, int lane, int valid)
{
#pragma unroll
    for (int it = 0; it < 4; ++it) {
        int rbase = wave * 32 + it * 8;          // wave-uniform
        int rloc  = rbase + (lane >> 3);
        int grow  = rloc < valid ? rloc : (valid - 1);
        int chunk = (lane & 7) ^ (rloc & 7);
        const bf16* g = gbase + (size_t)grow * KTOT + chunk * 8;
        async_load16(g, lds + rbase * 64);
    }
}

// fast exact-enough GELU: tanh form via one exp2 + one rcp (~8 VALU ops).
// |err| vs erf-GELU < ~1e-3 — far inside budget (bf16 mid rounding dominates).
__device__ static inline float fast_gelu(float v)
{
    // z = 2*sqrt(2/pi)*(v + 0.044715 v^3) * log2(e)
    float z = v * (2.302236479f + 0.1029451170f * v * v);
    float ex = __builtin_amdgcn_exp2f(z);              // e^{2u}
    return v * ex * __builtin_amdgcn_rcpf(ex + 1.f);   // v * sigmoid(2u)
}

// ---------------------------------------------------------------------------
// MFMA GEMM over tile list. A: [rows,KTOT] bf16. B: [E][NTOT][KTOT] bf16.
// 128x128 tile, BK=64, 4 waves x (64x64 via 4x4 mfma_16x16x32).
// ---------------------------------------------------------------------------
template<int KTOT, int NTOT, bool DOGELU, typename OutT>
__global__ __launch_bounds__(256, 4)
void moe_gemm(const bf16* __restrict__ Abase, const bf16* __restrict__ Bbase,
              const float* __restrict__ bias, OutT* __restrict__ Out,
              const int* __restrict__ tiles, const int* __restrict__ ntiles,
              const int* __restrict__ offsets)
{
    if (blockIdx.x >= *ntiles) return;
    int info = tiles[blockIdx.x];
    int e = info >> 24, row0 = info & 0xffffff;
    int valid = offsets[e + 1] - row0; if (valid > 128) valid = 128;
    int n0 = blockIdx.y * 128;

    const bf16* A = Abase + (size_t)row0 * KTOT;
    const bf16* B = Bbase + (size_t)e * NTOT * KTOT + (size_t)n0 * KTOT;
    const float* bvec = bias + (size_t)e * NTOT + n0;

    __shared__ __align__(16) bf16 As[128 * 64];
    __shared__ __align__(16) bf16 Bs[128 * 64];

    int tid = threadIdx.x;
    int lane = tid & 63, wave = tid >> 6;
    int wr = wave >> 1, wc = wave & 1;
    int m16 = lane & 15, quad = lane >> 4;
    int swz = m16 & 7;

    floatx4 acc[4][4];
#pragma unroll
    for (int i = 0; i < 4; ++i)
#pragma unroll
        for (int j = 0; j < 4; ++j)
#pragma unroll
            for (int r = 0; r < 4; ++r) acc[i][j][r] = 0.f;

    for (int k0 = 0; k0 < KTOT; k0 += 64) {
        stage_tile<KTOT>(A + k0, As, wave, lane, valid);
        stage_tile<KTOT>(B + k0, Bs, wave, lane, 128);
        __syncthreads();
#pragma unroll
        for (int ks = 0; ks < 64; ks += 32) {
            int cbase = (ks >> 3) + quad;
            int pchunk = (cbase ^ swz) * 8;
            bf16x8 af[4], bfr[4];
#pragma unroll
            for (int i = 0; i < 4; ++i)
                af[i] = *(const bf16x8*)(&As[(wr * 64 + i * 16 + m16) * 64 + pchunk]);
#pragma unroll
            for (int j = 0; j < 4; ++j)
                bfr[j] = *(const bf16x8*)(&Bs[(wc * 64 + j * 16 + m16) * 64 + pchunk]);
#pragma unroll
            for (int i = 0; i < 4; ++i)
#pragma unroll
                for (int j = 0; j < 4; ++j)
                    acc[i][j] = __builtin_amdgcn_mfma_f32_16x16x32_bf16(
                        af[i], bfr[j], acc[i][j], 0, 0, 0);
        }
        __syncthreads();
    }

    // epilogue: C/D layout col = lane&15, row = quad*4 + reg  [m89-verified]
#pragma unroll
    for (int i = 0; i < 4; ++i) {
#pragma unroll
        for (int r = 0; r < 4; ++r) {
            int lrow = wr * 64 + i * 16 + quad * 4 + r;
            if (lrow >= valid) continue;
            size_t orow = (size_t)(row0 + lrow) * NTOT + n0;
#pragma unroll
            for (int j = 0; j < 4; ++j) {
                int lcol = wc * 64 + j * 16 + m16;
                float v = acc[i][j][r] + bvec[lcol];
                if (DOGELU) v = fast_gelu(v);
                Out[orow + lcol] = (OutT)v;
            }
        }
    }
}

// ---------------------------------------------------------------------------
// Kernel 7: combine. out[t] = w0*y[pos0] + w1*y[pos1].
// ---------------------------------------------------------------------------
__global__ void combine_kernel(const float* __restrict__ y,
                               const int* __restrict__ offsets,
                               const int* __restrict__ selpack,
                               const int* __restrict__ slots,
                               const float* __restrict__ wts,
                               float* __restrict__ out)
{
    int t = blockIdx.x;
    int sp = selpack[t];
    int e0 = sp & 0xff, e1 = (sp >> 8) & 0xff;
    int p0 = offsets[e0] + slots[2 * t];
    int p1 = offsets[e1] + slots[2 * t + 1];
    float w0 = wts[2 * t], w1 = wts[2 * t + 1];
    const float4* y0 = (const float4*)(y + (size_t)p0 * DDIM);
    const float4* y1 = (const float4*)(y + (size_t)p1 * DDIM);
    float4* o = (float4*)(out + (size_t)t * DDIM);
    int tid = threadIdx.x;
    float4 a = y0[tid], b = y1[tid];
    float4 rr;
    rr.x = w0 * a.x + w1 * b.x;
    rr.y = w0 * a.y + w1 * b.y;
    rr.z = w0 * a.z + w1 * b.z;
    rr.w = w0 * a.w + w1 * b.w;
    o[tid] = rr;
}

// ---------------------------------------------------------------------------
extern "C" void kernel_launch(void* const* d_in, const int* in_sizes, int n_in,
                              void* d_out, int out_size, void* d_ws, size_t ws_size,
                              hipStream_t stream)
{
    (void)in_sizes; (void)n_in; (void)out_size; (void)ws_size;
    const float* x  = (const float*)d_in[0];
    const float* gw = (const float*)d_in[1];
    const float* gb = (const float*)d_in[2];
    const float* w1 = (const float*)d_in[3];
    const float* b1 = (const float*)d_in[4];
    const float* w2 = (const float*)d_in[5];
    const float* b2 = (const float*)d_in[6];
    float* out    = (float*)d_out;
    float* logits = out + (size_t)T_TOKENS * DDIM;

    char* ws = (char*)d_ws;
    const size_t MB = 1024 * 1024;
    int*   counts   = (int*)(ws + 0);
    int*   offsets  = (int*)(ws + 256);
    int*   tiles    = (int*)(ws + 512);                  // 136 ints
    int*   ntiles   = (int*)(ws + 512 + 1024);
    int*   selpack  = (int*)(ws + 4096);                 // 32 KB
    int*   slots    = (int*)(ws + 4096 + 32 * 1024);     // 64 KB
    float* wts      = (float*)(ws + 4096 + 96 * 1024);   // 64 KB
    int*   token_of = (int*)(ws + 4096 + 160 * 1024);    // 256 KB
    bf16*  xg  = (bf16*)(ws + 1 * MB);    // 32 MB
    bf16*  w1b = (bf16*)(ws + 33 * MB);   // [E][H][D] 64 MB
    bf16*  w2b = (bf16*)(ws + 97 * MB);   // [E][D][H] 64 MB
    bf16*  mid = (bf16*)(ws + 161 * MB);  // 128 MB
    float* y   = (float*)(ws + 289 * MB); // 64 MB

    hipMemsetAsync(counts, 0, 32, stream);

    router_kernel<<<T_TOKENS, 64, 0, stream>>>(x, gw, gb, logits, counts,
                                               token_of, selpack, slots, wts);
    offsets_kernel<<<1, 64, 0, stream>>>(counts, offsets, tiles, ntiles);
    gather_kernel<<<2 * T_TOKENS / 4, 256, 0, stream>>>(x, offsets, token_of, xg);
    // w1: [E][1024][4096] -> w1b [E][4096][1024]
    transpose_cvt_kernel<<<dim3(HDIM / 64, DDIM / 64, NEXP), 256, 0, stream>>>(
        w1, w1b, DDIM, HDIM);
    // w2: [E][4096][1024] -> w2b [E][1024][4096]
    transpose_cvt_kernel<<<dim3(DDIM / 64, HDIM / 64, NEXP), 256, 0, stream>>>(
        w2, w2b, HDIM, DDIM);
    // GEMM1: mid = gelu(xg @ w1[e] + b1[e])
    moe_gemm<DDIM, HDIM, true, bf16><<<dim3(MAXTILES, HDIM / 128), 256, 0, stream>>>(
        xg, w1b, b1, mid, tiles, ntiles, offsets);
    // GEMM2: y = mid @ w2[e] + b2[e]
    moe_gemm<HDIM, DDIM, false, float><<<dim3(MAXTILES, DDIM / 128), 256, 0, stream>>>(
        mid, w2b, b2, y, tiles, ntiles, offsets);
    combine_kernel<<<T_TOKENS, 256, 0, stream>>>(y, offsets, selpack, slots, wts, out);
}